// Round 12
// baseline (343.635 us; speedup 1.0000x reference)
//
#include <hip/hip_runtime.h>

#define NB 32
#define NT 2048
#define ND 1024
#define NU 1024
#define NM (NB*NT)   // 65536 rows

using f32x4 = __attribute__((ext_vector_type(4))) float;
using s16x8 = __attribute__((ext_vector_type(8))) short;

#define BAR()    asm volatile("s_barrier" ::: "memory")
#define LGKM0()  asm volatile("s_waitcnt lgkmcnt(0)" ::: "memory")
#define VMC(n)   asm volatile("s_waitcnt vmcnt(" #n ")" ::: "memory")
#define SB0()    __builtin_amdgcn_sched_barrier(0)
#define P1()     __builtin_amdgcn_s_setprio(1)
#define P0()     __builtin_amdgcn_s_setprio(0)

__device__ __forceinline__ unsigned short f2bf(float f) {
  unsigned u = __builtin_bit_cast(unsigned, f);
  u = u + 0x7fffu + ((u >> 16) & 1u);   // round-to-nearest-even
  return (unsigned short)(u >> 16);
}

__device__ __forceinline__ void gload_lds16(const void* g, void* l) {
  __builtin_amdgcn_global_load_lds(
      (const __attribute__((address_space(1))) unsigned int*)g,
      (__attribute__((address_space(3))) unsigned int*)l, 16, 0, 0);
}

__device__ __forceinline__ float tanh_fast(float x) {
  float e = __expf(2.0f * x);
  return 1.0f - 2.0f * __builtin_amdgcn_rcpf(e + 1.0f);
}

// Stage half-tile h (128 rows x 64 k bf16 = 16KB) of K-tile kt.
// WAVE-UNIFORM LDS dest (m104/m108 contract): base = lds + h*8192 + cb*512,
// HW writes lane at base + lane*16B. Global source per-lane, chunk pre-XOR'd:
// LDS[r][c] = G[r][c ^ (r&7)] (16B chunks). r3 = lane>>3, c8s = (lane&7)^r3.
__device__ __forceinline__ void stage_half(const unsigned short* g, int kt, int h,
                                           unsigned short* lds, int w, int r3, int c8s) {
#pragma unroll
  for (int i = 0; i < 2; ++i) {
    int cb = i * 8 + w;   // 16 blocks of 8 rows; wave-uniform
    gload_lds16(g + ((size_t)(h * 128 + cb * 8 + r3) << 10) + kt * 64 + c8s * 8,
                lds + h * 8192 + cb * 512);
  }
}

// fa[m][ks] over m-rows m0..m0+3 from A dbuf region (256 rows x 64, row=64 elems)
#define RD_FA(base, m0) \
  _Pragma("unroll") for (int m_ = 0; m_ < 4; ++m_) { \
    _Pragma("unroll") for (int ks_ = 0; ks_ < 2; ++ks_) { \
      int row_ = wr * 128 + ((m0) + m_) * 16 + l15; \
      int c_ = (ks_ * 4 + lg) ^ (row_ & 7); \
      fa[m_][ks_] = *(const s16x8*)((base) + row_ * 64 + c_ * 8); } }

#define RD_FB(dst, base, n0) \
  _Pragma("unroll") for (int n_ = 0; n_ < 2; ++n_) { \
    _Pragma("unroll") for (int ks_ = 0; ks_ < 2; ++ks_) { \
      int row_ = wc * 64 + ((n0) + n_) * 16 + l15; \
      int c_ = (ks_ * 4 + lg) ^ (row_ & 7); \
      (dst)[n_][ks_] = *(const s16x8*)((base) + row_ * 64 + c_ * 8); } }

#define MF(mb, fbx, nb) \
  _Pragma("unroll") for (int m_ = 0; m_ < 4; ++m_) \
    _Pragma("unroll") for (int n_ = 0; n_ < 2; ++n_) \
      _Pragma("unroll") for (int ks_ = 0; ks_ < 2; ++ks_) \
        acc[(mb) + m_][(nb) + n_] = __builtin_amdgcn_mfma_f32_16x16x32_bf16( \
            fa[m_][ks_], (fbx)[n_][ks_], acc[(mb) + m_][(nb) + n_], 0, 0, 0);

// One iteration = 2 K-tiles (2i in dbuf0, 2i+1 in dbuf1), 8 phases.
// Stage stream: ph1:A1(2i+1)->d1  ph2:B0(2i+1)->d1  ph3:B1(2i+1)->d1
// ph4:A0(2i+2)->d0 +VMC(2)  ph5:A1(2i+2)->d0  ph6:B0(2i+2)->d0
// ph7:B1(2i+2)->d0  ph8:A0(2i+3)->d1 +VMC(2).
// Ledger at ph4/ph8 VMC: 10 outstanding -> retire oldest 8 = the consumed
// K-tile's 4 halves. Region recycles are >=2 barriers after last read.
template<bool TAIL>
__device__ __forceinline__ void iter8(
    int i, const unsigned short* gA, const unsigned short* gB,
    unsigned short* sA, unsigned short* sB, f32x4 (&acc)[8][4],
    int w, int r3, int c8s, int wr, int wc, int l15, int lg) {
  const unsigned short* d0A = sA;
  const unsigned short* d0B = sB;
  const unsigned short* d1A = sA + 16384;
  const unsigned short* d1B = sB + 16384;
  s16x8 fa[4][2], fbA[2][2], fbB[2][2];
  const int kt0 = 2 * i;
  // ---- ph1: fa03 + fb01 (d0); stage A1(kt0+1)
  RD_FA(d0A, 0); RD_FB(fbA, d0B, 0);
  stage_half(gA, kt0 + 1, 1, sA + 16384, w, r3, c8s);
  BAR(); LGKM0(); SB0();
  P1(); MF(0, fbA, 0); P0();
  BAR();
  // ---- ph2: fb23 (d0); stage B0(kt0+1)
  RD_FB(fbB, d0B, 2);
  stage_half(gB, kt0 + 1, 0, sB + 16384, w, r3, c8s);
  BAR(); LGKM0(); SB0();
  P1(); MF(0, fbB, 2); P0();
  BAR();
  // ---- ph3: fa47 (d0); stage B1(kt0+1)
  RD_FA(d0A, 4);
  stage_half(gB, kt0 + 1, 1, sB + 16384, w, r3, c8s);
  BAR(); LGKM0(); SB0();
  P1(); MF(4, fbB, 2); P0();
  BAR();
  // ---- ph4: no reads (fbA live); stage A0(kt0+2); gate K-tile kt0+1
  if (!TAIL) { stage_half(gA, kt0 + 2, 0, sA, w, r3, c8s); VMC(2); }
  else { VMC(0); }
  BAR(); SB0();
  P1(); MF(4, fbA, 0); P0();
  BAR();
  // ---- ph5: fa03 + fb01 (d1); stage A1(kt0+2)
  RD_FA(d1A, 0); RD_FB(fbA, d1B, 0);
  if (!TAIL) stage_half(gA, kt0 + 2, 1, sA, w, r3, c8s);
  BAR(); LGKM0(); SB0();
  P1(); MF(0, fbA, 0); P0();
  BAR();
  // ---- ph6: fb23 (d1); stage B0(kt0+2)
  RD_FB(fbB, d1B, 2);
  if (!TAIL) stage_half(gB, kt0 + 2, 0, sB, w, r3, c8s);
  BAR(); LGKM0(); SB0();
  P1(); MF(0, fbB, 2); P0();
  BAR();
  // ---- ph7: fa47 (d1); stage B1(kt0+2)
  RD_FA(d1A, 4);
  if (!TAIL) stage_half(gB, kt0 + 2, 1, sB, w, r3, c8s);
  BAR(); LGKM0(); SB0();
  P1(); MF(4, fbB, 2); P0();
  BAR();
  // ---- ph8: no reads; stage A0(kt0+3); gate K-tile kt0+2
  if (!TAIL) { stage_half(gA, kt0 + 3, 0, sA + 16384, w, r3, c8s); VMC(2); }
  BAR(); SB0();
  P1(); MF(4, fbA, 0); P0();
  BAR();
}

// 256x256 tile, BK=64, 8-phase m201-style. score_part[4][65536].
// GRID = 1024 = 256 mtiles x 4 ntiles (R10/R11 bug: launched 2048 -> OOB).
__global__ __launch_bounds__(512, 2) void k_score_gemm8(
    const unsigned short* __restrict__ vbf, const unsigned short* __restrict__ W2t,
    const float* __restrict__ add2, const float* __restrict__ Vk,
    float* __restrict__ score_part) {
  __shared__ unsigned short sA[32768];   // 2 dbuf x 256 rows x 64 k
  __shared__ unsigned short sB[32768];
  const int tid = threadIdx.x;
  const int w = tid >> 6;
  const int lane = tid & 63;
  const int wr = w >> 2, wc = w & 3;     // 2M x 4N, wave-tile 128x64
  const int l15 = lane & 15, lg = lane >> 4;
  const int r3 = lane >> 3, c8s = (lane & 7) ^ r3;

  const int L = blockIdx.x;                 // 1024 blocks
  const int g = (L & 7) * 128 + (L >> 3);   // XCD-contiguous, bijective on 0..1023
  const int mtile = g >> 2, ntile = g & 3;  // mtile 0..255, ntile 0..3

  const unsigned short* gA = vbf + ((size_t)mtile << 18);
  const unsigned short* gB = W2t + ((size_t)ntile << 18);

  f32x4 acc[8][4] = {};

  // Prologue: K0 (4 halves)->d0, K1 A0->d1; retire K0 (VMC(2)).
  stage_half(gA, 0, 0, sA, w, r3, c8s);
  stage_half(gA, 0, 1, sA, w, r3, c8s);
  stage_half(gB, 0, 0, sB, w, r3, c8s);
  stage_half(gB, 0, 1, sB, w, r3, c8s);
  stage_half(gA, 1, 0, sA + 16384, w, r3, c8s);
  VMC(2);
  BAR();

#pragma unroll 1
  for (int i = 0; i < 7; ++i)
    iter8<false>(i, gA, gB, sA, sB, acc, w, r3, c8s, wr, wc, l15, lg);
  iter8<true>(7, gA, gB, sA, sB, acc, w, r3, c8s, wr, wc, l15, lg);

  // Epilogue: x = acc + add2[b][u]; row-sum of tanh(x)*Vk[u] over this 256-col slab
  const int b = (mtile * 256) >> 11;   // block-uniform
  float vks[4], adds[4];
#pragma unroll
  for (int n = 0; n < 4; ++n) {
    int u = ntile * 256 + wc * 64 + n * 16 + l15;
    vks[n] = Vk[u];
    adds[n] = add2[(b << 10) + u];
  }
  __syncthreads();
  float* part = (float*)sA;   // [4][256]
#pragma unroll
  for (int m = 0; m < 8; ++m) {
#pragma unroll
    for (int j = 0; j < 4; ++j) {
      float s = 0.f;
#pragma unroll
      for (int n = 0; n < 4; ++n) {
        float x = acc[m][n][j] + adds[n];
        s = fmaf(tanh_fast(x), vks[n], s);
      }
#pragma unroll
      for (int off = 1; off < 16; off <<= 1) s += __shfl_xor(s, off);
      if (l15 == 0) part[wc * 256 + wr * 128 + m * 16 + lg * 4 + j] = s;
    }
  }
  __syncthreads();
  if (tid < 256) {
    float v = part[tid] + part[256 + tid] + part[512 + tid] + part[768 + tid];
    score_part[((size_t)ntile << 16) + mtile * 256 + tid] = v;
  }
}

// add2[b][u] = query[b]·W1_k[:,u] + W1_b[u] + W2_b[u]
__global__ void k_qproj(const float* __restrict__ q, const float* __restrict__ W1,
                        const float* __restrict__ W1b, const float* __restrict__ W2b,
                        float* __restrict__ add2) {
  int u = blockIdx.x * 256 + threadIdx.x;
  int b = blockIdx.y;
  const float* qr = q + (b << 10);
  float s = 0.f;
#pragma unroll 8
  for (int d = 0; d < ND; ++d) s = fmaf(qr[d], W1[d * NU + u], s);
  add2[(b << 10) + u] = s + W1b[u] + W2b[u];
}

// W2_k [D][U] f32 -> W2t [U][D] bf16
__global__ void k_w2t(const float* __restrict__ W2, unsigned short* __restrict__ W2t) {
  __shared__ unsigned short tile[64][65];
  int bu = blockIdx.x * 64, bd = blockIdx.y * 64;
  int x = threadIdx.x & 63, y4 = threadIdx.x >> 6;
#pragma unroll
  for (int r = 0; r < 16; ++r) {
    int dl = y4 * 16 + r;
    tile[x][dl] = f2bf(W2[(size_t)(bd + dl) * NU + bu + x]);
  }
  __syncthreads();
#pragma unroll
  for (int r = 0; r < 16; ++r) {
    int ul = y4 * 16 + r;
    W2t[(size_t)(bu + ul) * ND + bd + x] = tile[ul][x];
  }
}

// values f32 -> bf16
__global__ void k_cvt_values(const float4* __restrict__ v, ushort4* __restrict__ o) {
  const int n4 = NM * ND / 4;
  for (int i = blockIdx.x * blockDim.x + threadIdx.x; i < n4; i += gridDim.x * blockDim.x) {
    float4 f = v[i];
    ushort4 h;
    h.x = f2bf(f.x); h.y = f2bf(f.y); h.z = f2bf(f.z); h.w = f2bf(f.w);
    o[i] = h;
  }
}

// softmax over T per batch; sums 4 N-tile partials first (deterministic)
__global__ void k_softmax(const float* __restrict__ sp, float* __restrict__ w) {
  __shared__ float redm[4], reds[4];
  int b = blockIdx.x, tid = threadIdx.x;
  float s[8];
  float mx = -1e30f;
#pragma unroll
  for (int i = 0; i < 8; ++i) {
    int t = i * 256 + tid;
    float v = 0.f;
#pragma unroll
    for (int p = 0; p < 4; ++p) v += sp[((size_t)p << 16) + (b << 11) + t];
    s[i] = v;
    mx = fmaxf(mx, v);
  }
#pragma unroll
  for (int o = 1; o < 64; o <<= 1) mx = fmaxf(mx, __shfl_xor(mx, o));
  if ((tid & 63) == 0) redm[tid >> 6] = mx;
  __syncthreads();
  mx = fmaxf(fmaxf(redm[0], redm[1]), fmaxf(redm[2], redm[3]));
  float sum = 0.f;
#pragma unroll
  for (int i = 0; i < 8; ++i) { s[i] = __expf(s[i] - mx); sum += s[i]; }
#pragma unroll
  for (int o = 1; o < 64; o <<= 1) sum += __shfl_xor(sum, o);
  if ((tid & 63) == 0) reds[tid >> 6] = sum;
  __syncthreads();
  float inv = 1.0f / (reds[0] + reds[1] + reds[2] + reds[3]);
#pragma unroll
  for (int i = 0; i < 8; ++i) w[(b << 11) + i * 256 + tid] = s[i] * inv;
}

// context partials over 16 t-chunks of 128: part[tc][b][d]
__global__ void k_context(const float* __restrict__ values, const float* __restrict__ wv,
                          float* __restrict__ part) {
  int d4 = threadIdx.x;
  int b = blockIdx.y, tc = blockIdx.z;
  const float4* vb = (const float4*)(values + ((size_t)b << 21) + ((size_t)tc << 17)) + d4;
  const float* wb = wv + (b << 11) + (tc << 7);
  float ax = 0.f, ay = 0.f, az = 0.f, aw = 0.f;
#pragma unroll 4
  for (int t = 0; t < 128; ++t) {
    float4 v = vb[(size_t)t << 8];
    float wt = wb[t];
    ax = fmaf(wt, v.x, ax); ay = fmaf(wt, v.y, ay);
    az = fmaf(wt, v.z, az); aw = fmaf(wt, v.w, aw);
  }
  float4* po = (float4*)(part + (((size_t)tc * NB + b) << 10)) + d4;
  *po = make_float4(ax, ay, az, aw);
}

__global__ void k_ctx_reduce(const float* __restrict__ part, float* __restrict__ out) {
  int i = blockIdx.x * 256 + threadIdx.x;  // 32768
  float s = 0.f;
#pragma unroll
  for (int p = 0; p < 16; ++p) s += part[(p << 15) + i];
  out[i] = s;
}

extern "C" void kernel_launch(void* const* d_in, const int* in_sizes, int n_in,
                              void* d_out, int out_size, void* d_ws, size_t ws_size,
                              hipStream_t stream) {
  const float* query  = (const float*)d_in[0];
  const float* values = (const float*)d_in[1];
  const float* W1k    = (const float*)d_in[2];
  const float* W1b    = (const float*)d_in[3];
  const float* W2k    = (const float*)d_in[4];
  const float* W2b    = (const float*)d_in[5];
  const float* Vk     = (const float*)d_in[6];
  // V_b dropped: softmax is shift-invariant.
  float* out = (float*)d_out;
  char* ws = (char*)d_ws;

  size_t off = 0;
  float* add2 = (float*)(ws + off); off += (size_t)NB * NU * 4;            // 128 KB
  float* sp   = (float*)(ws + off); off += (size_t)4 * NM * 4;             // 1 MB
  float* wv   = (float*)(ws + off); off += (size_t)NM * 4;                 // 256 KB
  float* ctxp = (float*)(ws + off); off += (size_t)16 * NB * ND * 4;       // 2 MB
  unsigned short* W2t = (unsigned short*)(ws + off); off += (size_t)NU * ND * 2; // 2 MB
  unsigned short* vbf = (unsigned short*)(ws + off); off += (size_t)NM * ND * 2; // 128 MB

  k_qproj<<<dim3(4, 32), 256, 0, stream>>>(query, W1k, W1b, W2b, add2);
  k_w2t<<<dim3(16, 16), 256, 0, stream>>>(W2k, W2t);
  k_cvt_values<<<dim3(2048), 256, 0, stream>>>((const float4*)values, (ushort4*)vbf);
  k_score_gemm8<<<dim3(1024), 512, 0, stream>>>(vbf, W2t, add2, Vk, sp);
  k_softmax<<<dim3(32), 256, 0, stream>>>(sp, wv);
  k_context<<<dim3(1, 32, 16), 256, 0, stream>>>(values, wv, ctxp);
  k_ctx_reduce<<<dim3(128), 256, 0, stream>>>(ctxp, out);
}